// Round 1
// baseline (164.144 us; speedup 1.0000x reference)
//
#include <hip/hip_runtime.h>

// ContextGenerator: B=32, D=NOTE_RES=64, T=4096, fp32.
// res[b,t] = sum_{L=low..min(63,up-1)} dm[b,L-1,t] * s_L[t]
// Group M (L=M+pad): s_L = P_M(pad) + sum_{k=pad}^{M-1} xC[k]*pm[k+pad].
//
// R8: software-pipelined multi-chunk blocks. R7's one-chunk-per-block grid is
// phase-aligned: all resident blocks stage together, then HBM idles during
// every compute phase, and the 2048-block grid pays 3 residency rounds of
// latency ramp. R8: 512 blocks x 4 chunks, 2 blocks/CU fully co-resident;
// each iteration issues next chunk's 8x per-lane dwordx4 loads (T14 split)
// BEFORE computing the current chunk from LDS, so compute hides load latency
// and the memory pipe stays busy. Roles/LDS layout identical to R7 (verified).

#define TT 4096
#define NCHUNK 4

// Coarse-term k-range [K0, K0+8) of group32 (M=32).
template <int K0>
__device__ __forceinline__ float roleK(const float* __restrict__ lrep,
                                       const float* __restrict__ lpm,
                                       const float* __restrict__ ldm, int lane,
                                       int low, int up) {
  constexpr int PADN = (K0 + 8 < 32) ? (K0 + 8) : 32;  // pads 0..PADN-1
  constexpr int PMN = (2 * K0 + 14 < 62 ? 2 * K0 + 14 : 62) - K0 + 1;
  float xa[8];  // x1[K0..K0+7]
#pragma unroll
  for (int i = 0; i < 8; ++i)
    xa[i] = 0.5f * (lrep[(2 * (K0 + i)) * 64 + lane] +
                    lrep[(2 * (K0 + i) + 1) * 64 + lane]);
  float pmv[PMN];
#pragma unroll
  for (int r = 0; r < PMN; ++r) pmv[r] = lpm[(K0 + r) * 64 + lane];
  float res = 0.f;
#pragma unroll
  for (int pad = 0; pad < PADN; ++pad) {
    const int L = 32 + pad;
    const int kk0 = (pad > K0) ? pad : K0;
    float s = 0.f;
#pragma unroll
    for (int k = kk0; k < K0 + 8; ++k)
      s = fmaf(xa[k - K0], pmv[k + pad - K0], s);
    if (L >= low && L < up) res = fmaf(ldm[(31 + pad) * 64 + lane], s, res);
  }
  return res;
}

// w3: group32 coarse k in [0,8)  +  the whole M=16 level.
__device__ __forceinline__ float role3(const float* __restrict__ lrep,
                                       const float* __restrict__ lpm,
                                       const float* __restrict__ ldm, int lane,
                                       int low, int up) {
  float pmv[31];  // pm rows 0..30
#pragma unroll
  for (int r = 0; r < 31; ++r) pmv[r] = lpm[r * 64 + lane];
  float x1[32];
#pragma unroll
  for (int j = 0; j < 32; ++j)
    x1[j] = 0.5f * (lrep[(2 * j) * 64 + lane] + lrep[(2 * j + 1) * 64 + lane]);
  float res = 0.f;
#pragma unroll
  for (int pad = 0; pad < 8; ++pad) {
    const int L = 32 + pad;
    float s = 0.f;
#pragma unroll
    for (int k = pad; k < 8; ++k) s = fmaf(x1[k], pmv[k + pad], s);
    if (L >= low && L < up) res = fmaf(ldm[(31 + pad) * 64 + lane], s, res);
  }
  float x2[16], q1[16];
#pragma unroll
  for (int j = 0; j < 16; ++j) {
    const float a = x1[2 * j], bb = x1[2 * j + 1];
    x2[j] = 0.5f * (a + bb);
    q1[j] = a * pmv[2 * j] + bb * pmv[2 * j + 1];
  }
  float p = 0.f;
#pragma unroll
  for (int pad = 0; pad < 16; ++pad) {
    const int L = 16 + pad;
    float s = p;
#pragma unroll
    for (int k = pad; k < 16; ++k) s = fmaf(x2[k], pmv[k + pad], s);
    if (L >= low && L < up) res = fmaf(ldm[(15 + pad) * 64 + lane], s, res);
    p += q1[pad];
  }
  return res;
}

// w4: group32 fine-prefix duty.
__device__ __forceinline__ float role4(const float* __restrict__ lrep,
                                       const float* __restrict__ lpm,
                                       const float* __restrict__ ldm, int lane,
                                       int low, int up) {
  float res = 0.f, p = 0.f;
#pragma unroll
  for (int pad = 1; pad < 32; ++pad) {
    const int j = pad - 1;
    p = fmaf(lrep[(2 * j) * 64 + lane], lpm[(2 * j) * 64 + lane],
             fmaf(lrep[(2 * j + 1) * 64 + lane], lpm[(2 * j + 1) * 64 + lane],
                  p));
    const int L = 32 + pad;
    if (L >= low && L < up) res = fmaf(ldm[(31 + pad) * 64 + lane], p, res);
  }
  return res;
}

// w5: M=8,4,2,1 levels.
template <int M>
__device__ __forceinline__ void level_step(const float* pmv,
                                           const float* __restrict__ ldm,
                                           int lane, int low, int up, float* xf,
                                           float* xc, float& res) {
  float q[M];
#pragma unroll
  for (int j = 0; j < M; ++j) {
    const float a = xf[2 * j], bb = xf[2 * j + 1];
    xc[j] = 0.5f * (a + bb);
    q[j] = a * pmv[2 * j] + bb * pmv[2 * j + 1];
  }
  float p = 0.f;
#pragma unroll
  for (int pad = 0; pad < M; ++pad) {
    const int L = M + pad;
    float s = p;
#pragma unroll
    for (int k = pad; k < M; ++k) s = fmaf(xc[k], pmv[k + pad], s);
    if (L >= low && L < up) res = fmaf(ldm[(M - 1 + pad) * 64 + lane], s, res);
    p += q[pad];
  }
}

__device__ __forceinline__ float role5(const float* __restrict__ lrep,
                                       const float* __restrict__ lpm,
                                       const float* __restrict__ ldm, int lane,
                                       int low, int up) {
  float pmv[15];  // pm rows 0..14
#pragma unroll
  for (int r = 0; r < 15; ++r) pmv[r] = lpm[r * 64 + lane];
  float x1[32];
#pragma unroll
  for (int j = 0; j < 32; ++j)
    x1[j] = 0.5f * (lrep[(2 * j) * 64 + lane] + lrep[(2 * j + 1) * 64 + lane]);
  float x2[16];
#pragma unroll
  for (int j = 0; j < 16; ++j) x2[j] = 0.5f * (x1[2 * j] + x1[2 * j + 1]);
  float res = 0.f;
  float x3[8], x4[4], x5[2], x6[1];
  level_step<8>(pmv, ldm, lane, low, up, x2, x3, res);
  level_step<4>(pmv, ldm, lane, low, up, x3, x4, res);
  level_step<2>(pmv, ldm, lane, low, up, x4, x5, res);
  level_step<1>(pmv, ldm, lane, low, up, x5, x6, res);
  return res;
}

__global__ __launch_bounds__(384, 3) void ContextGenerator_34875134444049_kernel(
    const float* __restrict__ rep, const float* __restrict__ dm,
    const float* __restrict__ pm, const int* __restrict__ lowp,
    const int* __restrict__ upp, float* __restrict__ out) {
  // 192 data rows (64 rep | 64 pm | 64 dm) * 256 B + 6*64 partials = 50688 B
  __shared__ float lds[192 * 64 + 6 * 64];
  const int tid = threadIdx.x;
  const int wid = tid >> 6;
  const int lane = tid & 63;

  const int low = lowp[0];
  const int up = upp[0];

  // Chunk c in [0,2048): b = c>>6, t0 = (c&63)<<6. Each block owns 4
  // consecutive chunks (64 chunks per batch -> no block straddles b).
  const int c0 = blockIdx.x * NCHUNK;

  // Per-thread staging geometry: slot s = tid + 384*g, row = s>>4 (0..191),
  // float4 col = s&15. Row 0..63 = rep, 64..127 = pm, 128..191 = dm.
  float4 v[8];

  // --- prologue: load + stage chunk 0 ---
  {
    const int c = c0;
    const size_t base = (size_t)(c >> 6) * 64 * TT + (size_t)((c & 63) << 6);
#pragma unroll
    for (int g = 0; g < 8; ++g) {
      const int slot = tid + 384 * g;
      const int row = slot >> 4;
      const int c4 = (slot & 15) << 2;
      const float* tb = (row < 64) ? rep + base + (size_t)row * TT
                      : (row < 128) ? pm + base + (size_t)(row - 64) * TT
                                    : dm + base + (size_t)(row - 128) * TT;
      v[g] = *(const float4*)(tb + c4);
    }
#pragma unroll
    for (int g = 0; g < 8; ++g) {
      const int slot = tid + 384 * g;
      *(float4*)(&lds[slot << 2]) = v[g];
    }
  }

  const float* lrep = lds;
  const float* lpm = lds + 64 * 64;
  const float* ldm = lds + 128 * 64;
  float* part = lds + 192 * 64;

#pragma unroll 1
  for (int i = 0; i < NCHUNK; ++i) {
    __syncthreads();  // B1: staged LDS data for chunk i visible

    // T14 async-STAGE split: issue next chunk's global loads NOW; they drain
    // under the ~2 us compute phase below.
    if (i + 1 < NCHUNK) {
      const int c = c0 + i + 1;
      const size_t base = (size_t)(c >> 6) * 64 * TT + (size_t)((c & 63) << 6);
#pragma unroll
      for (int g = 0; g < 8; ++g) {
        const int slot = tid + 384 * g;
        const int row = slot >> 4;
        const int c4 = (slot & 15) << 2;
        const float* tb = (row < 64) ? rep + base + (size_t)row * TT
                        : (row < 128) ? pm + base + (size_t)(row - 64) * TT
                                      : dm + base + (size_t)(row - 128) * TT;
        v[g] = *(const float4*)(tb + c4);
      }
    }

    float res;
    if (wid == 0)
      res = roleK<24>(lrep, lpm, ldm, lane, low, up);
    else if (wid == 1)
      res = roleK<16>(lrep, lpm, ldm, lane, low, up);
    else if (wid == 2)
      res = roleK<8>(lrep, lpm, ldm, lane, low, up);
    else if (wid == 3)
      res = role3(lrep, lpm, ldm, lane, low, up);
    else if (wid == 4)
      res = role4(lrep, lpm, ldm, lane, low, up);
    else
      res = role5(lrep, lpm, ldm, lane, low, up);

    if (wid > 0) part[wid * 64 + lane] = res;
    __syncthreads();  // B2: all LDS data reads for chunk i done; partials in

    if (wid == 0) {
      const int c = c0 + i;
      out[(size_t)(c >> 6) * TT + (size_t)((c & 63) << 6) + lane] =
          res + part[64 + lane] + part[128 + lane] + part[192 + lane] +
          part[256 + lane] + part[320 + lane];
    }

    // Overwrite data region with chunk i+1 (safe: reads done at B2; wave0
    // only touches the disjoint partials region between B2 and next B1).
    if (i + 1 < NCHUNK) {
#pragma unroll
      for (int g = 0; g < 8; ++g) {
        const int slot = tid + 384 * g;
        *(float4*)(&lds[slot << 2]) = v[g];
      }
    }
  }
}

extern "C" void kernel_launch(void* const* d_in, const int* in_sizes, int n_in,
                              void* d_out, int out_size, void* d_ws,
                              size_t ws_size, hipStream_t stream) {
  const float* rep = (const float*)d_in[0];
  const float* dm = (const float*)d_in[1];
  const float* pm = (const float*)d_in[2];
  const int* lowp = (const int*)d_in[3];
  const int* upp = (const int*)d_in[4];
  float* out = (float*)d_out;

  const int blocks = out_size / (64 * NCHUNK);  // 131072/256 = 512
  ContextGenerator_34875134444049_kernel<<<blocks, 384, 0, stream>>>(
      rep, dm, pm, lowp, upp, out);
}

// Round 2
// 161.070 us; speedup vs baseline: 1.0191x; 1.0191x over previous
//
#include <hip/hip_runtime.h>

// ContextGenerator: B=32, D=NOTE_RES=64, T=4096, fp32.
// res[b,t] = sum_{L=low..min(63,up-1)} dm[b,L-1,t] * s_L[t]
// Group M (L=M+pad): s_L = P_M(pad) + sum_{k=pad}^{M-1} xC[k]*pm[k+pad].
//
// R9: fix R8's scratch-spill regression. R8 held v[8] (32 VGPR) across the
// role bodies under __launch_bounds__(384,3) (VGPR cap ~170) -> allocator
// spilled the role arrays to scratch (rocprof: VGPR=68, WRITE_SIZE=69MB vs
// ideal 0.5MB, kernel 69us). R9 keeps the same prefetch pipeline but relaxes
// to __launch_bounds__(384,2) (cap 256: roles ~130 + v[8] 32 fits, no spill)
// and goes to NCHUNK=8 / 256 blocks = exactly 1 block/CU, one residency
// round. The block's own prefetch (48KB in flight/CU) covers HBM latency;
// compute (~0.4us/chunk) hides under staging (~2us/chunk) -> pure streaming.

#define TT 4096
#define NCHUNK 8

// Coarse-term k-range [K0, K0+8) of group32 (M=32).
template <int K0>
__device__ __forceinline__ float roleK(const float* __restrict__ lrep,
                                       const float* __restrict__ lpm,
                                       const float* __restrict__ ldm, int lane,
                                       int low, int up) {
  constexpr int PADN = (K0 + 8 < 32) ? (K0 + 8) : 32;  // pads 0..PADN-1
  constexpr int PMN = (2 * K0 + 14 < 62 ? 2 * K0 + 14 : 62) - K0 + 1;
  float xa[8];  // x1[K0..K0+7]
#pragma unroll
  for (int i = 0; i < 8; ++i)
    xa[i] = 0.5f * (lrep[(2 * (K0 + i)) * 64 + lane] +
                    lrep[(2 * (K0 + i) + 1) * 64 + lane]);
  float pmv[PMN];
#pragma unroll
  for (int r = 0; r < PMN; ++r) pmv[r] = lpm[(K0 + r) * 64 + lane];
  float res = 0.f;
#pragma unroll
  for (int pad = 0; pad < PADN; ++pad) {
    const int L = 32 + pad;
    const int kk0 = (pad > K0) ? pad : K0;
    float s = 0.f;
#pragma unroll
    for (int k = kk0; k < K0 + 8; ++k)
      s = fmaf(xa[k - K0], pmv[k + pad - K0], s);
    if (L >= low && L < up) res = fmaf(ldm[(31 + pad) * 64 + lane], s, res);
  }
  return res;
}

// w3: group32 coarse k in [0,8)  +  the whole M=16 level.
__device__ __forceinline__ float role3(const float* __restrict__ lrep,
                                       const float* __restrict__ lpm,
                                       const float* __restrict__ ldm, int lane,
                                       int low, int up) {
  float pmv[31];  // pm rows 0..30
#pragma unroll
  for (int r = 0; r < 31; ++r) pmv[r] = lpm[r * 64 + lane];
  float x1[32];
#pragma unroll
  for (int j = 0; j < 32; ++j)
    x1[j] = 0.5f * (lrep[(2 * j) * 64 + lane] + lrep[(2 * j + 1) * 64 + lane]);
  float res = 0.f;
#pragma unroll
  for (int pad = 0; pad < 8; ++pad) {
    const int L = 32 + pad;
    float s = 0.f;
#pragma unroll
    for (int k = pad; k < 8; ++k) s = fmaf(x1[k], pmv[k + pad], s);
    if (L >= low && L < up) res = fmaf(ldm[(31 + pad) * 64 + lane], s, res);
  }
  float x2[16], q1[16];
#pragma unroll
  for (int j = 0; j < 16; ++j) {
    const float a = x1[2 * j], bb = x1[2 * j + 1];
    x2[j] = 0.5f * (a + bb);
    q1[j] = a * pmv[2 * j] + bb * pmv[2 * j + 1];
  }
  float p = 0.f;
#pragma unroll
  for (int pad = 0; pad < 16; ++pad) {
    const int L = 16 + pad;
    float s = p;
#pragma unroll
    for (int k = pad; k < 16; ++k) s = fmaf(x2[k], pmv[k + pad], s);
    if (L >= low && L < up) res = fmaf(ldm[(15 + pad) * 64 + lane], s, res);
    p += q1[pad];
  }
  return res;
}

// w4: group32 fine-prefix duty.
__device__ __forceinline__ float role4(const float* __restrict__ lrep,
                                       const float* __restrict__ lpm,
                                       const float* __restrict__ ldm, int lane,
                                       int low, int up) {
  float res = 0.f, p = 0.f;
#pragma unroll
  for (int pad = 1; pad < 32; ++pad) {
    const int j = pad - 1;
    p = fmaf(lrep[(2 * j) * 64 + lane], lpm[(2 * j) * 64 + lane],
             fmaf(lrep[(2 * j + 1) * 64 + lane], lpm[(2 * j + 1) * 64 + lane],
                  p));
    const int L = 32 + pad;
    if (L >= low && L < up) res = fmaf(ldm[(31 + pad) * 64 + lane], p, res);
  }
  return res;
}

// w5: M=8,4,2,1 levels.
template <int M>
__device__ __forceinline__ void level_step(const float* pmv,
                                           const float* __restrict__ ldm,
                                           int lane, int low, int up, float* xf,
                                           float* xc, float& res) {
  float q[M];
#pragma unroll
  for (int j = 0; j < M; ++j) {
    const float a = xf[2 * j], bb = xf[2 * j + 1];
    xc[j] = 0.5f * (a + bb);
    q[j] = a * pmv[2 * j] + bb * pmv[2 * j + 1];
  }
  float p = 0.f;
#pragma unroll
  for (int pad = 0; pad < M; ++pad) {
    const int L = M + pad;
    float s = p;
#pragma unroll
    for (int k = pad; k < M; ++k) s = fmaf(xc[k], pmv[k + pad], s);
    if (L >= low && L < up) res = fmaf(ldm[(M - 1 + pad) * 64 + lane], s, res);
    p += q[pad];
  }
}

__device__ __forceinline__ float role5(const float* __restrict__ lrep,
                                       const float* __restrict__ lpm,
                                       const float* __restrict__ ldm, int lane,
                                       int low, int up) {
  float pmv[15];  // pm rows 0..14
#pragma unroll
  for (int r = 0; r < 15; ++r) pmv[r] = lpm[r * 64 + lane];
  float x1[32];
#pragma unroll
  for (int j = 0; j < 32; ++j)
    x1[j] = 0.5f * (lrep[(2 * j) * 64 + lane] + lrep[(2 * j + 1) * 64 + lane]);
  float x2[16];
#pragma unroll
  for (int j = 0; j < 16; ++j) x2[j] = 0.5f * (x1[2 * j] + x1[2 * j + 1]);
  float res = 0.f;
  float x3[8], x4[4], x5[2], x6[1];
  level_step<8>(pmv, ldm, lane, low, up, x2, x3, res);
  level_step<4>(pmv, ldm, lane, low, up, x3, x4, res);
  level_step<2>(pmv, ldm, lane, low, up, x4, x5, res);
  level_step<1>(pmv, ldm, lane, low, up, x5, x6, res);
  return res;
}

__global__ __launch_bounds__(384, 2) void ContextGenerator_34875134444049_kernel(
    const float* __restrict__ rep, const float* __restrict__ dm,
    const float* __restrict__ pm, const int* __restrict__ lowp,
    const int* __restrict__ upp, float* __restrict__ out) {
  // 192 data rows (64 rep | 64 pm | 64 dm) * 256 B + 6*64 partials = 50688 B
  __shared__ float lds[192 * 64 + 6 * 64];
  const int tid = threadIdx.x;
  const int wid = tid >> 6;
  const int lane = tid & 63;

  const int low = lowp[0];
  const int up = upp[0];

  // Chunk c in [0,2048): b = c>>6, t0 = (c&63)<<6. Each block owns 8
  // consecutive chunks (64 chunks per batch, 64%8==0 -> no batch straddle).
  const int c0 = blockIdx.x * NCHUNK;

  // Per-thread staging geometry: slot s = tid + 384*g, row = s>>4 (0..191),
  // float4 col = s&15. Row 0..63 = rep, 64..127 = pm, 128..191 = dm.
  float4 v[8];

  // --- prologue: load + stage chunk 0 ---
  {
    const int c = c0;
    const size_t base = (size_t)(c >> 6) * 64 * TT + (size_t)((c & 63) << 6);
#pragma unroll
    for (int g = 0; g < 8; ++g) {
      const int slot = tid + 384 * g;
      const int row = slot >> 4;
      const int c4 = (slot & 15) << 2;
      const float* tb = (row < 64) ? rep + base + (size_t)row * TT
                      : (row < 128) ? pm + base + (size_t)(row - 64) * TT
                                    : dm + base + (size_t)(row - 128) * TT;
      v[g] = *(const float4*)(tb + c4);
    }
#pragma unroll
    for (int g = 0; g < 8; ++g) {
      const int slot = tid + 384 * g;
      *(float4*)(&lds[slot << 2]) = v[g];
    }
  }

  const float* lrep = lds;
  const float* lpm = lds + 64 * 64;
  const float* ldm = lds + 128 * 64;
  float* part = lds + 192 * 64;

#pragma unroll 1
  for (int i = 0; i < NCHUNK; ++i) {
    __syncthreads();  // B1: staged LDS data for chunk i visible

    // Issue next chunk's global loads NOW; they drain under compute below
    // and the pipe stays busy during the post-B2 waitcnt.
    if (i + 1 < NCHUNK) {
      const int c = c0 + i + 1;
      const size_t base = (size_t)(c >> 6) * 64 * TT + (size_t)((c & 63) << 6);
#pragma unroll
      for (int g = 0; g < 8; ++g) {
        const int slot = tid + 384 * g;
        const int row = slot >> 4;
        const int c4 = (slot & 15) << 2;
        const float* tb = (row < 64) ? rep + base + (size_t)row * TT
                        : (row < 128) ? pm + base + (size_t)(row - 64) * TT
                                      : dm + base + (size_t)(row - 128) * TT;
        v[g] = *(const float4*)(tb + c4);
      }
    }

    float res;
    if (wid == 0)
      res = roleK<24>(lrep, lpm, ldm, lane, low, up);
    else if (wid == 1)
      res = roleK<16>(lrep, lpm, ldm, lane, low, up);
    else if (wid == 2)
      res = roleK<8>(lrep, lpm, ldm, lane, low, up);
    else if (wid == 3)
      res = role3(lrep, lpm, ldm, lane, low, up);
    else if (wid == 4)
      res = role4(lrep, lpm, ldm, lane, low, up);
    else
      res = role5(lrep, lpm, ldm, lane, low, up);

    if (wid > 0) part[wid * 64 + lane] = res;
    __syncthreads();  // B2: all LDS data reads for chunk i done; partials in

    if (wid == 0) {
      const int c = c0 + i;
      out[(size_t)(c >> 6) * TT + (size_t)((c & 63) << 6) + lane] =
          res + part[64 + lane] + part[128 + lane] + part[192 + lane] +
          part[256 + lane] + part[320 + lane];
    }

    // Overwrite data region with chunk i+1 (safe: reads done at B2; wave0
    // only touches the disjoint partials region between B2 and next B1).
    if (i + 1 < NCHUNK) {
#pragma unroll
      for (int g = 0; g < 8; ++g) {
        const int slot = tid + 384 * g;
        *(float4*)(&lds[slot << 2]) = v[g];
      }
    }
  }
}

extern "C" void kernel_launch(void* const* d_in, const int* in_sizes, int n_in,
                              void* d_out, int out_size, void* d_ws,
                              size_t ws_size, hipStream_t stream) {
  const float* rep = (const float*)d_in[0];
  const float* dm = (const float*)d_in[1];
  const float* pm = (const float*)d_in[2];
  const int* lowp = (const int*)d_in[3];
  const int* upp = (const int*)d_in[4];
  float* out = (float*)d_out;

  const int blocks = out_size / (64 * NCHUNK);  // 131072/512 = 256
  ContextGenerator_34875134444049_kernel<<<blocks, 384, 0, stream>>>(
      rep, dm, pm, lowp, upp, out);
}

// Round 3
// 127.846 us; speedup vs baseline: 1.2839x; 1.2599x over previous
//
#include <hip/hip_runtime.h>

// ContextGenerator: B=32, D=NOTE_RES=64, T=4096, fp32.
// res[b,t] = sum_{L=low..min(63,up-1)} dm[b,L-1,t] * s_L[t]
// Group M (L=M+pad): s_L = P_M(pad) + sum_{k=pad}^{M-1} xC[k]*pm[k+pad].
//
// R10: de-scratch the prefetch pipeline. R8/R9 showed identical VGPR=68 under
// launch_bounds (384,3) AND (384,2) with WRITE_SIZE 69/43 MB vs ideal 0.5 MB:
// the cap was never binding -> float4 v[8] (aggregate, conditional defs inside
// a #pragma unroll 1 loop) failed SROA and lived in scratch (rule #20).
// 43 MB = 98304 thr x 7 chunks x 64 B round-trip, matching exactly.
// R10 = R9 with v[8] replaced by named scalars v0..v7 (scalar promotion is
// unconditional). Structure, roles, LDS layout, grid unchanged.

#define TT 4096
#define NCHUNK 8

// Coarse-term k-range [K0, K0+8) of group32 (M=32).
template <int K0>
__device__ __forceinline__ float roleK(const float* __restrict__ lrep,
                                       const float* __restrict__ lpm,
                                       const float* __restrict__ ldm, int lane,
                                       int low, int up) {
  constexpr int PADN = (K0 + 8 < 32) ? (K0 + 8) : 32;  // pads 0..PADN-1
  constexpr int PMN = (2 * K0 + 14 < 62 ? 2 * K0 + 14 : 62) - K0 + 1;
  float xa[8];  // x1[K0..K0+7]
#pragma unroll
  for (int i = 0; i < 8; ++i)
    xa[i] = 0.5f * (lrep[(2 * (K0 + i)) * 64 + lane] +
                    lrep[(2 * (K0 + i) + 1) * 64 + lane]);
  float pmv[PMN];
#pragma unroll
  for (int r = 0; r < PMN; ++r) pmv[r] = lpm[(K0 + r) * 64 + lane];
  float res = 0.f;
#pragma unroll
  for (int pad = 0; pad < PADN; ++pad) {
    const int L = 32 + pad;
    const int kk0 = (pad > K0) ? pad : K0;
    float s = 0.f;
#pragma unroll
    for (int k = kk0; k < K0 + 8; ++k)
      s = fmaf(xa[k - K0], pmv[k + pad - K0], s);
    if (L >= low && L < up) res = fmaf(ldm[(31 + pad) * 64 + lane], s, res);
  }
  return res;
}

// w3: group32 coarse k in [0,8)  +  the whole M=16 level.
__device__ __forceinline__ float role3(const float* __restrict__ lrep,
                                       const float* __restrict__ lpm,
                                       const float* __restrict__ ldm, int lane,
                                       int low, int up) {
  float pmv[31];  // pm rows 0..30
#pragma unroll
  for (int r = 0; r < 31; ++r) pmv[r] = lpm[r * 64 + lane];
  float x1[32];
#pragma unroll
  for (int j = 0; j < 32; ++j)
    x1[j] = 0.5f * (lrep[(2 * j) * 64 + lane] + lrep[(2 * j + 1) * 64 + lane]);
  float res = 0.f;
#pragma unroll
  for (int pad = 0; pad < 8; ++pad) {
    const int L = 32 + pad;
    float s = 0.f;
#pragma unroll
    for (int k = pad; k < 8; ++k) s = fmaf(x1[k], pmv[k + pad], s);
    if (L >= low && L < up) res = fmaf(ldm[(31 + pad) * 64 + lane], s, res);
  }
  float x2[16], q1[16];
#pragma unroll
  for (int j = 0; j < 16; ++j) {
    const float a = x1[2 * j], bb = x1[2 * j + 1];
    x2[j] = 0.5f * (a + bb);
    q1[j] = a * pmv[2 * j] + bb * pmv[2 * j + 1];
  }
  float p = 0.f;
#pragma unroll
  for (int pad = 0; pad < 16; ++pad) {
    const int L = 16 + pad;
    float s = p;
#pragma unroll
    for (int k = pad; k < 16; ++k) s = fmaf(x2[k], pmv[k + pad], s);
    if (L >= low && L < up) res = fmaf(ldm[(15 + pad) * 64 + lane], s, res);
    p += q1[pad];
  }
  return res;
}

// w4: group32 fine-prefix duty.
__device__ __forceinline__ float role4(const float* __restrict__ lrep,
                                       const float* __restrict__ lpm,
                                       const float* __restrict__ ldm, int lane,
                                       int low, int up) {
  float res = 0.f, p = 0.f;
#pragma unroll
  for (int pad = 1; pad < 32; ++pad) {
    const int j = pad - 1;
    p = fmaf(lrep[(2 * j) * 64 + lane], lpm[(2 * j) * 64 + lane],
             fmaf(lrep[(2 * j + 1) * 64 + lane], lpm[(2 * j + 1) * 64 + lane],
                  p));
    const int L = 32 + pad;
    if (L >= low && L < up) res = fmaf(ldm[(31 + pad) * 64 + lane], p, res);
  }
  return res;
}

// w5: M=8,4,2,1 levels.
template <int M>
__device__ __forceinline__ void level_step(const float* pmv,
                                           const float* __restrict__ ldm,
                                           int lane, int low, int up, float* xf,
                                           float* xc, float& res) {
  float q[M];
#pragma unroll
  for (int j = 0; j < M; ++j) {
    const float a = xf[2 * j], bb = xf[2 * j + 1];
    xc[j] = 0.5f * (a + bb);
    q[j] = a * pmv[2 * j] + bb * pmv[2 * j + 1];
  }
  float p = 0.f;
#pragma unroll
  for (int pad = 0; pad < M; ++pad) {
    const int L = M + pad;
    float s = p;
#pragma unroll
    for (int k = pad; k < M; ++k) s = fmaf(xc[k], pmv[k + pad], s);
    if (L >= low && L < up) res = fmaf(ldm[(M - 1 + pad) * 64 + lane], s, res);
    p += q[pad];
  }
}

__device__ __forceinline__ float role5(const float* __restrict__ lrep,
                                       const float* __restrict__ lpm,
                                       const float* __restrict__ ldm, int lane,
                                       int low, int up) {
  float pmv[15];  // pm rows 0..14
#pragma unroll
  for (int r = 0; r < 15; ++r) pmv[r] = lpm[r * 64 + lane];
  float x1[32];
#pragma unroll
  for (int j = 0; j < 32; ++j)
    x1[j] = 0.5f * (lrep[(2 * j) * 64 + lane] + lrep[(2 * j + 1) * 64 + lane]);
  float x2[16];
#pragma unroll
  for (int j = 0; j < 16; ++j) x2[j] = 0.5f * (x1[2 * j] + x1[2 * j + 1]);
  float res = 0.f;
  float x3[8], x4[4], x5[2], x6[1];
  level_step<8>(pmv, ldm, lane, low, up, x2, x3, res);
  level_step<4>(pmv, ldm, lane, low, up, x3, x4, res);
  level_step<2>(pmv, ldm, lane, low, up, x4, x5, res);
  level_step<1>(pmv, ldm, lane, low, up, x5, x6, res);
  return res;
}

// One float4 of chunk data for staging slot `slot` (= tid + 384*g).
// Rows 0..63 = rep, 64..127 = pm, 128..191 = dm; float4 col = slot&15.
__device__ __forceinline__ float4 ld1(const float* __restrict__ rep,
                                      const float* __restrict__ pm,
                                      const float* __restrict__ dm, size_t base,
                                      int slot) {
  const int row = slot >> 4;
  const int c4 = (slot & 15) << 2;
  const float* tb = (row < 64) ? rep + base + (size_t)row * TT
                  : (row < 128) ? pm + base + (size_t)(row - 64) * TT
                                : dm + base + (size_t)(row - 128) * TT;
  return *(const float4*)(tb + c4);
}

#define LOAD_CHUNK(c)                                                         \
  do {                                                                        \
    const size_t base_ =                                                      \
        (size_t)((c) >> 6) * (64 * TT) + (size_t)(((c) & 63) << 6);           \
    v0 = ld1(rep, pm, dm, base_, tid + 384 * 0);                              \
    v1 = ld1(rep, pm, dm, base_, tid + 384 * 1);                              \
    v2 = ld1(rep, pm, dm, base_, tid + 384 * 2);                              \
    v3 = ld1(rep, pm, dm, base_, tid + 384 * 3);                              \
    v4 = ld1(rep, pm, dm, base_, tid + 384 * 4);                              \
    v5 = ld1(rep, pm, dm, base_, tid + 384 * 5);                              \
    v6 = ld1(rep, pm, dm, base_, tid + 384 * 6);                              \
    v7 = ld1(rep, pm, dm, base_, tid + 384 * 7);                              \
  } while (0)

#define STORE_CHUNK()                                                         \
  do {                                                                        \
    *(float4*)(&lds[(tid + 384 * 0) << 2]) = v0;                              \
    *(float4*)(&lds[(tid + 384 * 1) << 2]) = v1;                              \
    *(float4*)(&lds[(tid + 384 * 2) << 2]) = v2;                              \
    *(float4*)(&lds[(tid + 384 * 3) << 2]) = v3;                              \
    *(float4*)(&lds[(tid + 384 * 4) << 2]) = v4;                              \
    *(float4*)(&lds[(tid + 384 * 5) << 2]) = v5;                              \
    *(float4*)(&lds[(tid + 384 * 6) << 2]) = v6;                              \
    *(float4*)(&lds[(tid + 384 * 7) << 2]) = v7;                              \
  } while (0)

__global__ __launch_bounds__(384, 2) void ContextGenerator_34875134444049_kernel(
    const float* __restrict__ rep, const float* __restrict__ dm,
    const float* __restrict__ pm, const int* __restrict__ lowp,
    const int* __restrict__ upp, float* __restrict__ out) {
  // 192 data rows (64 rep | 64 pm | 64 dm) * 256 B + 6*64 partials = 50688 B
  __shared__ float lds[192 * 64 + 6 * 64];
  const int tid = threadIdx.x;
  const int wid = tid >> 6;
  const int lane = tid & 63;

  const int low = lowp[0];
  const int up = upp[0];

  // Chunk c in [0,2048): b = c>>6, t0 = (c&63)<<6. Each block owns 8
  // consecutive chunks (64 chunks per batch, 64%8==0 -> no batch straddle).
  const int c0 = blockIdx.x * NCHUNK;

  // Named scalars (NOT an array): guarantees SROA keeps the prefetch in
  // registers across the role compute. 32 VGPRs; cap under (384,2) is 256.
  float4 v0, v1, v2, v3, v4, v5, v6, v7;

  // --- prologue: load + stage chunk 0 ---
  LOAD_CHUNK(c0);
  STORE_CHUNK();

  const float* lrep = lds;
  const float* lpm = lds + 64 * 64;
  const float* ldm = lds + 128 * 64;
  float* part = lds + 192 * 64;

#pragma unroll 1
  for (int i = 0; i < NCHUNK; ++i) {
    __syncthreads();  // B1: staged LDS data for chunk i visible

    // Issue next chunk's global loads NOW; they drain under compute below.
    if (i + 1 < NCHUNK) {
      LOAD_CHUNK(c0 + i + 1);
    }

    float res;
    if (wid == 0)
      res = roleK<24>(lrep, lpm, ldm, lane, low, up);
    else if (wid == 1)
      res = roleK<16>(lrep, lpm, ldm, lane, low, up);
    else if (wid == 2)
      res = roleK<8>(lrep, lpm, ldm, lane, low, up);
    else if (wid == 3)
      res = role3(lrep, lpm, ldm, lane, low, up);
    else if (wid == 4)
      res = role4(lrep, lpm, ldm, lane, low, up);
    else
      res = role5(lrep, lpm, ldm, lane, low, up);

    if (wid > 0) part[wid * 64 + lane] = res;
    __syncthreads();  // B2: all LDS data reads for chunk i done; partials in

    if (wid == 0) {
      const int c = c0 + i;
      out[(size_t)(c >> 6) * TT + (size_t)((c & 63) << 6) + lane] =
          res + part[64 + lane] + part[128 + lane] + part[192 + lane] +
          part[256 + lane] + part[320 + lane];
    }

    // Overwrite data region with chunk i+1 (safe: reads done at B2; wave0
    // only touches the disjoint partials region between B2 and next B1).
    if (i + 1 < NCHUNK) {
      STORE_CHUNK();
    }
  }
}

extern "C" void kernel_launch(void* const* d_in, const int* in_sizes, int n_in,
                              void* d_out, int out_size, void* d_ws,
                              size_t ws_size, hipStream_t stream) {
  const float* rep = (const float*)d_in[0];
  const float* dm = (const float*)d_in[1];
  const float* pm = (const float*)d_in[2];
  const int* lowp = (const int*)d_in[3];
  const int* upp = (const int*)d_in[4];
  float* out = (float*)d_out;

  const int blocks = out_size / (64 * NCHUNK);  // 131072/512 = 256
  ContextGenerator_34875134444049_kernel<<<blocks, 384, 0, stream>>>(
      rep, dm, pm, lowp, upp, out);
}

// Round 4
// 125.861 us; speedup vs baseline: 1.3042x; 1.0158x over previous
//
#include <hip/hip_runtime.h>

// ContextGenerator: B=32, D=NOTE_RES=64, T=4096, fp32.
// res[b,t] = sum_{L=low..min(63,up-1)} dm[b,L-1,t] * s_L[t]
// Group M (L=M+pad): s_L = P_M(pad) + sum_{k=pad}^{M-1} xC[k]*pm[k+pad].
//
// R11: channel de-correlation. R7 (3 blk/CU one-shot) and R10 (1 blk/CU,
// 8-deep pipeline, spill-free) BOTH plateau at ~40us ~2.4TB/s for 98MB of
// compulsory traffic -> ceiling is the address pattern, not the schedule.
// Each chunk reads 256-B slices of 192 rows strided 16KB; 16KB stride keeps
// HBM channel-select bits (~[8:13]) constant, and the old c=blk*8+i mapping
// put all concurrent blocks on ~8 distinct t-offsets mod 16KB -> channel
// starvation. R11 maps c = blockIdx + 256*i: t0=(blk&63)<<6 is distinct
// across blocks mod 64, so the 256 resident blocks cover ALL 64 channel
// positions at every instant. Everything else identical to R10.

#define TT 4096
#define NCHUNK 8

// Coarse-term k-range [K0, K0+8) of group32 (M=32).
template <int K0>
__device__ __forceinline__ float roleK(const float* __restrict__ lrep,
                                       const float* __restrict__ lpm,
                                       const float* __restrict__ ldm, int lane,
                                       int low, int up) {
  constexpr int PADN = (K0 + 8 < 32) ? (K0 + 8) : 32;  // pads 0..PADN-1
  constexpr int PMN = (2 * K0 + 14 < 62 ? 2 * K0 + 14 : 62) - K0 + 1;
  float xa[8];  // x1[K0..K0+7]
#pragma unroll
  for (int i = 0; i < 8; ++i)
    xa[i] = 0.5f * (lrep[(2 * (K0 + i)) * 64 + lane] +
                    lrep[(2 * (K0 + i) + 1) * 64 + lane]);
  float pmv[PMN];
#pragma unroll
  for (int r = 0; r < PMN; ++r) pmv[r] = lpm[(K0 + r) * 64 + lane];
  float res = 0.f;
#pragma unroll
  for (int pad = 0; pad < PADN; ++pad) {
    const int L = 32 + pad;
    const int kk0 = (pad > K0) ? pad : K0;
    float s = 0.f;
#pragma unroll
    for (int k = kk0; k < K0 + 8; ++k)
      s = fmaf(xa[k - K0], pmv[k + pad - K0], s);
    if (L >= low && L < up) res = fmaf(ldm[(31 + pad) * 64 + lane], s, res);
  }
  return res;
}

// w3: group32 coarse k in [0,8)  +  the whole M=16 level.
__device__ __forceinline__ float role3(const float* __restrict__ lrep,
                                       const float* __restrict__ lpm,
                                       const float* __restrict__ ldm, int lane,
                                       int low, int up) {
  float pmv[31];  // pm rows 0..30
#pragma unroll
  for (int r = 0; r < 31; ++r) pmv[r] = lpm[r * 64 + lane];
  float x1[32];
#pragma unroll
  for (int j = 0; j < 32; ++j)
    x1[j] = 0.5f * (lrep[(2 * j) * 64 + lane] + lrep[(2 * j + 1) * 64 + lane]);
  float res = 0.f;
#pragma unroll
  for (int pad = 0; pad < 8; ++pad) {
    const int L = 32 + pad;
    float s = 0.f;
#pragma unroll
    for (int k = pad; k < 8; ++k) s = fmaf(x1[k], pmv[k + pad], s);
    if (L >= low && L < up) res = fmaf(ldm[(31 + pad) * 64 + lane], s, res);
  }
  float x2[16], q1[16];
#pragma unroll
  for (int j = 0; j < 16; ++j) {
    const float a = x1[2 * j], bb = x1[2 * j + 1];
    x2[j] = 0.5f * (a + bb);
    q1[j] = a * pmv[2 * j] + bb * pmv[2 * j + 1];
  }
  float p = 0.f;
#pragma unroll
  for (int pad = 0; pad < 16; ++pad) {
    const int L = 16 + pad;
    float s = p;
#pragma unroll
    for (int k = pad; k < 16; ++k) s = fmaf(x2[k], pmv[k + pad], s);
    if (L >= low && L < up) res = fmaf(ldm[(15 + pad) * 64 + lane], s, res);
    p += q1[pad];
  }
  return res;
}

// w4: group32 fine-prefix duty.
__device__ __forceinline__ float role4(const float* __restrict__ lrep,
                                       const float* __restrict__ lpm,
                                       const float* __restrict__ ldm, int lane,
                                       int low, int up) {
  float res = 0.f, p = 0.f;
#pragma unroll
  for (int pad = 1; pad < 32; ++pad) {
    const int j = pad - 1;
    p = fmaf(lrep[(2 * j) * 64 + lane], lpm[(2 * j) * 64 + lane],
             fmaf(lrep[(2 * j + 1) * 64 + lane], lpm[(2 * j + 1) * 64 + lane],
                  p));
    const int L = 32 + pad;
    if (L >= low && L < up) res = fmaf(ldm[(31 + pad) * 64 + lane], p, res);
  }
  return res;
}

// w5: M=8,4,2,1 levels.
template <int M>
__device__ __forceinline__ void level_step(const float* pmv,
                                           const float* __restrict__ ldm,
                                           int lane, int low, int up, float* xf,
                                           float* xc, float& res) {
  float q[M];
#pragma unroll
  for (int j = 0; j < M; ++j) {
    const float a = xf[2 * j], bb = xf[2 * j + 1];
    xc[j] = 0.5f * (a + bb);
    q[j] = a * pmv[2 * j] + bb * pmv[2 * j + 1];
  }
  float p = 0.f;
#pragma unroll
  for (int pad = 0; pad < M; ++pad) {
    const int L = M + pad;
    float s = p;
#pragma unroll
    for (int k = pad; k < M; ++k) s = fmaf(xc[k], pmv[k + pad], s);
    if (L >= low && L < up) res = fmaf(ldm[(M - 1 + pad) * 64 + lane], s, res);
    p += q[pad];
  }
}

__device__ __forceinline__ float role5(const float* __restrict__ lrep,
                                       const float* __restrict__ lpm,
                                       const float* __restrict__ ldm, int lane,
                                       int low, int up) {
  float pmv[15];  // pm rows 0..14
#pragma unroll
  for (int r = 0; r < 15; ++r) pmv[r] = lpm[r * 64 + lane];
  float x1[32];
#pragma unroll
  for (int j = 0; j < 32; ++j)
    x1[j] = 0.5f * (lrep[(2 * j) * 64 + lane] + lrep[(2 * j + 1) * 64 + lane]);
  float x2[16];
#pragma unroll
  for (int j = 0; j < 16; ++j) x2[j] = 0.5f * (x1[2 * j] + x1[2 * j + 1]);
  float res = 0.f;
  float x3[8], x4[4], x5[2], x6[1];
  level_step<8>(pmv, ldm, lane, low, up, x2, x3, res);
  level_step<4>(pmv, ldm, lane, low, up, x3, x4, res);
  level_step<2>(pmv, ldm, lane, low, up, x4, x5, res);
  level_step<1>(pmv, ldm, lane, low, up, x5, x6, res);
  return res;
}

// One float4 of chunk data for staging slot `slot` (= tid + 384*g).
// Rows 0..63 = rep, 64..127 = pm, 128..191 = dm; float4 col = slot&15.
__device__ __forceinline__ float4 ld1(const float* __restrict__ rep,
                                      const float* __restrict__ pm,
                                      const float* __restrict__ dm, size_t base,
                                      int slot) {
  const int row = slot >> 4;
  const int c4 = (slot & 15) << 2;
  const float* tb = (row < 64) ? rep + base + (size_t)row * TT
                  : (row < 128) ? pm + base + (size_t)(row - 64) * TT
                                : dm + base + (size_t)(row - 128) * TT;
  return *(const float4*)(tb + c4);
}

#define LOAD_CHUNK(c)                                                         \
  do {                                                                        \
    const size_t base_ =                                                      \
        (size_t)((c) >> 6) * (64 * TT) + (size_t)(((c) & 63) << 6);           \
    v0 = ld1(rep, pm, dm, base_, tid + 384 * 0);                              \
    v1 = ld1(rep, pm, dm, base_, tid + 384 * 1);                              \
    v2 = ld1(rep, pm, dm, base_, tid + 384 * 2);                              \
    v3 = ld1(rep, pm, dm, base_, tid + 384 * 3);                              \
    v4 = ld1(rep, pm, dm, base_, tid + 384 * 4);                              \
    v5 = ld1(rep, pm, dm, base_, tid + 384 * 5);                              \
    v6 = ld1(rep, pm, dm, base_, tid + 384 * 6);                              \
    v7 = ld1(rep, pm, dm, base_, tid + 384 * 7);                              \
  } while (0)

#define STORE_CHUNK()                                                         \
  do {                                                                        \
    *(float4*)(&lds[(tid + 384 * 0) << 2]) = v0;                              \
    *(float4*)(&lds[(tid + 384 * 1) << 2]) = v1;                              \
    *(float4*)(&lds[(tid + 384 * 2) << 2]) = v2;                              \
    *(float4*)(&lds[(tid + 384 * 3) << 2]) = v3;                              \
    *(float4*)(&lds[(tid + 384 * 4) << 2]) = v4;                              \
    *(float4*)(&lds[(tid + 384 * 5) << 2]) = v5;                              \
    *(float4*)(&lds[(tid + 384 * 6) << 2]) = v6;                              \
    *(float4*)(&lds[(tid + 384 * 7) << 2]) = v7;                              \
  } while (0)

__global__ __launch_bounds__(384, 2) void ContextGenerator_34875134444049_kernel(
    const float* __restrict__ rep, const float* __restrict__ dm,
    const float* __restrict__ pm, const int* __restrict__ lowp,
    const int* __restrict__ upp, float* __restrict__ out) {
  // 192 data rows (64 rep | 64 pm | 64 dm) * 256 B + 6*64 partials = 50688 B
  __shared__ float lds[192 * 64 + 6 * 64];
  const int tid = threadIdx.x;
  const int wid = tid >> 6;
  const int lane = tid & 63;

  const int low = lowp[0];
  const int up = upp[0];

  // Chunk c in [0,2048): b = c>>6, t0 = (c&63)<<6. Swizzled assignment:
  // block j handles c = j + 256*i for i in [0,8). t0 = (j&63)<<6 is fixed
  // per block and distinct across blocks mod 64 -> concurrent blocks cover
  // all 64 channel positions of the 16KB row period. Bijective over [0,2048).
  const int j = blockIdx.x;

  // Named scalars (NOT an array): guarantees SROA keeps the prefetch in
  // registers across the role compute. 32 VGPRs; cap under (384,2) is 256.
  float4 v0, v1, v2, v3, v4, v5, v6, v7;

  // --- prologue: load + stage chunk 0 ---
  LOAD_CHUNK(j);
  STORE_CHUNK();

  const float* lrep = lds;
  const float* lpm = lds + 64 * 64;
  const float* ldm = lds + 128 * 64;
  float* part = lds + 192 * 64;

#pragma unroll 1
  for (int i = 0; i < NCHUNK; ++i) {
    __syncthreads();  // B1: staged LDS data for chunk i visible

    // Issue next chunk's global loads NOW; they drain under compute below.
    if (i + 1 < NCHUNK) {
      LOAD_CHUNK(j + 256 * (i + 1));
    }

    float res;
    if (wid == 0)
      res = roleK<24>(lrep, lpm, ldm, lane, low, up);
    else if (wid == 1)
      res = roleK<16>(lrep, lpm, ldm, lane, low, up);
    else if (wid == 2)
      res = roleK<8>(lrep, lpm, ldm, lane, low, up);
    else if (wid == 3)
      res = role3(lrep, lpm, ldm, lane, low, up);
    else if (wid == 4)
      res = role4(lrep, lpm, ldm, lane, low, up);
    else
      res = role5(lrep, lpm, ldm, lane, low, up);

    if (wid > 0) part[wid * 64 + lane] = res;
    __syncthreads();  // B2: all LDS data reads for chunk i done; partials in

    if (wid == 0) {
      const int c = j + 256 * i;
      out[(size_t)(c >> 6) * TT + (size_t)((c & 63) << 6) + lane] =
          res + part[64 + lane] + part[128 + lane] + part[192 + lane] +
          part[256 + lane] + part[320 + lane];
    }

    // Overwrite data region with chunk i+1 (safe: reads done at B2; wave0
    // only touches the disjoint partials region between B2 and next B1).
    if (i + 1 < NCHUNK) {
      STORE_CHUNK();
    }
  }
}

extern "C" void kernel_launch(void* const* d_in, const int* in_sizes, int n_in,
                              void* d_out, int out_size, void* d_ws,
                              size_t ws_size, hipStream_t stream) {
  const float* rep = (const float*)d_in[0];
  const float* dm = (const float*)d_in[1];
  const float* pm = (const float*)d_in[2];
  const int* lowp = (const int*)d_in[3];
  const int* upp = (const int*)d_in[4];
  float* out = (float*)d_out;

  const int blocks = out_size / (64 * NCHUNK);  // 131072/512 = 256
  ContextGenerator_34875134444049_kernel<<<blocks, 384, 0, stream>>>(
      rep, dm, pm, lowp, upp, out);
}